// Round 1
// baseline (193.488 us; speedup 1.0000x reference)
//
#include <hip/hip_runtime.h>
#include <math.h>

#define B_ 4
#define L_ 2048
#define S_ 2048
#define H_ 8
#define E_ 64

typedef short bf16x8 __attribute__((ext_vector_type(8)));
typedef float f32x4 __attribute__((ext_vector_type(4)));
typedef unsigned short u16x4 __attribute__((ext_vector_type(4)));

__device__ __forceinline__ unsigned short f2b(float f) {
  union { float f; unsigned u; } x; x.f = f;
  unsigned r = x.u + 0x7FFFu + ((x.u >> 16) & 1u);
  return (unsigned short)(r >> 16);
}

// Flash attention fwd, causal, tau-scaled. One block = 4 waves = 64 q-rows.
// Each wave owns 16 q-rows. KV tiles of 64. bf16 MFMA 16x16x32, f32 softmax.
__global__ __launch_bounds__(256) void attn_fwd(
    const float* __restrict__ Q, const float* __restrict__ K,
    const float* __restrict__ V, const float* __restrict__ tau,
    float* __restrict__ O)
{
  const int qt = blockIdx.x, h = blockIdx.y, b = blockIdx.z;
  const int tid  = threadIdx.x;
  const int wave = tid >> 6, lane = tid & 63;
  const int lg = lane >> 4, ll = lane & 15;

  // K tile [kv][e], V tile transposed [d][kv], P per-wave [q][kv].
  // All bf16, row stride 64 elems (128B), XOR-swizzled at 16B granularity:
  // granule_index ^= (row & 7)  -> ds_read_b128 fragment reads are ~2-way.
  __shared__ unsigned short ldsK[64 * 64];
  __shared__ unsigned short ldsV[64 * 64];
  __shared__ unsigned short ldsP[4][16 * 64];

  const float sc  = 0.125f * expf(tau[b]);   // 1/sqrt(64) * exp(tau)
  const float L2E = 1.44269504088896f;

  const int q0 = qt * 64 + wave * 16;        // this wave's first q-row

  // Q fragments (A operand): lane holds Q[q0 + ll][ek*32 + lg*8 + j], j=0..7
  const float* Qb = Q + (((size_t)b * L_ + (q0 + ll)) * H_ + h) * E_;
  bf16x8 qf[2];
  #pragma unroll
  for (int ek = 0; ek < 2; ++ek) {
    const f32x4* p = (const f32x4*)(Qb + ek * 32 + lg * 8);
    f32x4 a = p[0], c = p[1];
    #pragma unroll
    for (int j = 0; j < 4; ++j) {
      qf[ek][j]     = (short)f2b(a[j]);
      qf[ek][4 + j] = (short)f2b(c[j]);
    }
  }

  float m_r[4], l_r[4];
  f32x4 oacc[4];
  #pragma unroll
  for (int r = 0; r < 4; ++r) { m_r[r] = -INFINITY; l_r[r] = 0.0f; }
  #pragma unroll
  for (int n = 0; n < 4; ++n) {
    oacc[n][0] = 0.f; oacc[n][1] = 0.f; oacc[n][2] = 0.f; oacc[n][3] = 0.f;
  }

  const float* Kb = K + ((size_t)b * S_ * H_ + h) * E_;
  const float* Vb = V + ((size_t)b * S_ * H_ + h) * E_;

  const int rowq = tid >> 4;        // 0..15, staging row helper
  const int colq = (tid & 15) * 4;  // 0..60, staging col (float4)

  const int nt = qt + 1;            // causal: kv tiles [0, (qt+1)*64)
  for (int t = 0; t < nt; ++t) {
    const int s0 = t * 64;
    __syncthreads();                // prior iteration's LDS reads done

    // ---- stage K tile and V^T tile (f32 -> bf16), coalesced reads ----
    #pragma unroll
    for (int i = 0; i < 4; ++i) {
      const int row = i * 16 + rowq;                    // kv row in tile
      const float* kp = Kb + (size_t)(s0 + row) * (H_ * E_) + colq;
      const float* vp = Vb + (size_t)(s0 + row) * (H_ * E_) + colq;
      f32x4 k4 = *(const f32x4*)kp;
      f32x4 v4 = *(const f32x4*)vp;
      u16x4 ks;
      #pragma unroll
      for (int j = 0; j < 4; ++j) ks[j] = f2b(k4[j]);
      *(u16x4*)(&ldsK[row * 64 + (((colq >> 3) ^ (row & 7)) << 3) + (colq & 7)]) = ks;
      #pragma unroll
      for (int j = 0; j < 4; ++j) {                     // V^T scatter
        const int d = colq + j;
        ldsV[d * 64 + (((row >> 3) ^ (d & 7)) << 3) + (row & 7)] = f2b(v4[j]);
      }
    }
    __syncthreads();

    // ---- S = Q K^T (16 q x 64 kv per wave), 8 MFMAs ----
    f32x4 sacc[4];
    #pragma unroll
    for (int n = 0; n < 4; ++n) {
      sacc[n][0] = 0.f; sacc[n][1] = 0.f; sacc[n][2] = 0.f; sacc[n][3] = 0.f;
    }
    #pragma unroll
    for (int n = 0; n < 4; ++n) {
      const int krow = n * 16 + ll;                     // kv index (B n-col)
      #pragma unroll
      for (int ek = 0; ek < 2; ++ek) {
        const int ec = ek * 32 + lg * 8;                // e offset
        bf16x8 kf = *(const bf16x8*)(&ldsK[krow * 64 + (((ec >> 3) ^ (krow & 7)) << 3)]);
        sacc[n] = __builtin_amdgcn_mfma_f32_16x16x32_bf16(qf[ek], kf, sacc[n], 0, 0, 0);
      }
    }

    // ---- scale + causal mask (diagonal tile only) ----
    const bool diag = (t == nt - 1);
    #pragma unroll
    for (int n = 0; n < 4; ++n) {
      const int kvg = s0 + n * 16 + ll;
      #pragma unroll
      for (int r = 0; r < 4; ++r) {
        float v = sacc[n][r] * sc;
        if (diag && kvg > q0 + lg * 4 + r) v = -1e30f;
        sacc[n][r] = v;
      }
    }

    // ---- online softmax (per q-row: reg r + 16-lane group) ----
    unsigned short* Pl = &ldsP[wave][0];
    #pragma unroll
    for (int r = 0; r < 4; ++r) {
      float mx = fmaxf(fmaxf(sacc[0][r], sacc[1][r]), fmaxf(sacc[2][r], sacc[3][r]));
      mx = fmaxf(mx, __shfl_xor(mx, 1));
      mx = fmaxf(mx, __shfl_xor(mx, 2));
      mx = fmaxf(mx, __shfl_xor(mx, 4));
      mx = fmaxf(mx, __shfl_xor(mx, 8));
      const float mnew = fmaxf(m_r[r], mx);
      const float corr = exp2f((m_r[r] - mnew) * L2E);  // first tile: exp2(-inf)=0
      m_r[r] = mnew;
      float rs = 0.0f;
      #pragma unroll
      for (int n = 0; n < 4; ++n) {
        const float p = exp2f((sacc[n][r] - mnew) * L2E);
        sacc[n][r] = p;
        rs += p;
      }
      rs += __shfl_xor(rs, 1);
      rs += __shfl_xor(rs, 2);
      rs += __shfl_xor(rs, 4);
      rs += __shfl_xor(rs, 8);
      l_r[r] = l_r[r] * corr + rs;
      #pragma unroll
      for (int n = 0; n < 4; ++n) oacc[n][r] *= corr;
      // write P (bf16) to per-wave LDS, D-layout -> memory [q][kv], swizzled
      const int prow = lg * 4 + r;
      #pragma unroll
      for (int n = 0; n < 4; ++n) {
        const int pcol = n * 16 + ll;
        Pl[prow * 64 + (((pcol >> 3) ^ (prow & 7)) << 3) + (pcol & 7)] = f2b(sacc[n][r]);
      }
    }

    // ---- O += P V (8 MFMAs); P re-read in A-layout, V^T as B operand ----
    #pragma unroll
    for (int kk = 0; kk < 2; ++kk) {
      const int kv0 = kk * 32 + lg * 8;
      bf16x8 pf = *(const bf16x8*)(&Pl[ll * 64 + (((kv0 >> 3) ^ (ll & 7)) << 3)]);
      #pragma unroll
      for (int n = 0; n < 4; ++n) {
        const int d = n * 16 + ll;
        bf16x8 vf = *(const bf16x8*)(&ldsV[d * 64 + (((kv0 >> 3) ^ (d & 7)) << 3)]);
        oacc[n] = __builtin_amdgcn_mfma_f32_16x16x32_bf16(pf, vf, oacc[n], 0, 0, 0);
      }
    }
  }

  // ---- epilogue: normalize and store f32 ----
  float* Ob = O + (((size_t)b * L_ + q0) * H_ + h) * E_;
  #pragma unroll
  for (int r = 0; r < 4; ++r) {
    const float inv = 1.0f / l_r[r];
    const int qrow = lg * 4 + r;
    #pragma unroll
    for (int n = 0; n < 4; ++n) {
      Ob[(size_t)qrow * (H_ * E_) + n * 16 + ll] = oacc[n][r] * inv;
    }
  }
}

extern "C" void kernel_launch(void* const* d_in, const int* in_sizes, int n_in,
                              void* d_out, int out_size, void* d_ws, size_t ws_size,
                              hipStream_t stream) {
  (void)in_sizes; (void)n_in; (void)out_size; (void)d_ws; (void)ws_size;
  const float* Q   = (const float*)d_in[0];
  const float* K   = (const float*)d_in[1];
  const float* V   = (const float*)d_in[2];
  // d_in[3] = attn_mask: ignored, causality applied analytically.
  const float* tau = (const float*)d_in[4];
  float* O = (float*)d_out;
  dim3 grid(L_ / 64, H_, B_), block(256);
  hipLaunchKernelGGL(attn_fwd, grid, block, 0, stream, Q, K, V, tau, O);
}

// Round 2
// 116.535 us; speedup vs baseline: 1.6603x; 1.6603x over previous
//
#include <hip/hip_runtime.h>
#include <hip/hip_bf16.h>
#include <math.h>

#define B_ 4
#define L_ 2048
#define S_ 2048
#define H_ 8
#define E_ 64
#define HE (H_ * E_)
#define LDSTR 72   // padded LDS row stride in bf16 elems; 144 B keeps 16B alignment

typedef short bf16x8 __attribute__((ext_vector_type(8)));
typedef float f32x4 __attribute__((ext_vector_type(4)));
typedef unsigned short u16x4 __attribute__((ext_vector_type(4)));

__device__ __forceinline__ unsigned short f2b(float f) {
  return __builtin_bit_cast(unsigned short, (__hip_bfloat16)f);
}

// Flash attention fwd, causal, tau-scaled. Block = 4 waves = 64 q-rows.
// KV tiles of 64. bf16 MFMA 16x16x32, f32 log2-domain online softmax.
__global__ __launch_bounds__(256) void attn_fwd(
    const float* __restrict__ Q, const float* __restrict__ K,
    const float* __restrict__ V, const float* __restrict__ tau,
    float* __restrict__ O)
{
  // ---- balanced block remap: CU's 4 blocks get qt {j,15-j,16+j,31-j} ----
  const int fid = blockIdx.x + 32 * blockIdx.y + 256 * blockIdx.z;  // 0..1023
  const int g  = fid >> 5;          // 0..31
  const int hb = fid & 31;          // (b,h): all qt of one (b,h) share an XCD
  const int h  = hb & 7, b = hb >> 3;
  const int jj = g & 7, ss = g >> 3;
  const int qt = (ss == 0) ? jj : (ss == 1) ? 15 - jj : (ss == 2) ? 16 + jj : 31 - jj;

  const int tid  = threadIdx.x;
  const int wave = tid >> 6, lane = tid & 63;
  const int lg = lane >> 4, ll = lane & 15;

  __shared__ unsigned short ldsK[64 * LDSTR];        // [kv][e]
  __shared__ unsigned short ldsV[64 * LDSTR];        // transposed [d][kv]
  __shared__ unsigned short ldsP[4][16 * LDSTR];     // per-wave [q][kv]

  // fold 1/sqrt(E) * exp(tau) * log2(e) into Q  -> softmax in exp2 domain
  const float qscale = 0.125f * expf(tau[b]) * 1.44269504088896f;

  const int q0 = qt * 64 + wave * 16;

  // Q fragments (A operand): lane holds Q[q0+ll][ek*32 + lg*8 + j], j=0..7
  const float* Qb = Q + (((size_t)b * L_ + (q0 + ll)) * H_ + h) * E_;
  bf16x8 qf[2];
  #pragma unroll
  for (int ek = 0; ek < 2; ++ek) {
    const f32x4* p = (const f32x4*)(Qb + ek * 32 + lg * 8);
    f32x4 a = p[0], c4 = p[1];
    #pragma unroll
    for (int j = 0; j < 4; ++j) {
      qf[ek][j]     = (short)f2b(a[j] * qscale);
      qf[ek][4 + j] = (short)f2b(c4[j] * qscale);
    }
  }

  float m_r[4], l_r[4];
  f32x4 oacc[4];
  #pragma unroll
  for (int r = 0; r < 4; ++r) { m_r[r] = -INFINITY; l_r[r] = 0.0f; }
  #pragma unroll
  for (int n = 0; n < 4; ++n) {
    oacc[n][0] = 0.f; oacc[n][1] = 0.f; oacc[n][2] = 0.f; oacc[n][3] = 0.f;
  }

  const int rq = tid >> 4;          // 0..15 staging row helper
  const int cq = (tid & 15) * 4;    // 0..60 staging col (float4)

  const float* Kt = K + ((size_t)b * S_ * H_ + h) * E_;   // advance by tile
  const float* Vt = V + ((size_t)b * S_ * H_ + h) * E_;

  const int nt = qt + 1;            // causal: kv tiles [0, (qt+1)*64)
  for (int t = 0; t < nt; ++t) {
    __syncthreads();                // prior iteration's LDS reads done

    // ---- stage K [kv][e]: 4 rows x 4 cols per thread, vector writes ----
    #pragma unroll
    for (int i = 0; i < 4; ++i) {
      const int row = i * 16 + rq;
      f32x4 k4 = *(const f32x4*)(Kt + (size_t)row * HE + cq);
      u16x4 ks;
      #pragma unroll
      for (int j = 0; j < 4; ++j) ks[j] = f2b(k4[j]);
      *(u16x4*)(&ldsK[row * LDSTR + cq]) = ks;
    }
    // ---- stage V^T [d][kv]: 4x4 register-transposed block per thread ----
    {
      f32x4 v4[4];
      #pragma unroll
      for (int i = 0; i < 4; ++i)
        v4[i] = *(const f32x4*)(Vt + (size_t)(rq * 4 + i) * HE + cq);
      #pragma unroll
      for (int j = 0; j < 4; ++j) {
        u16x4 vs;
        #pragma unroll
        for (int i = 0; i < 4; ++i) vs[i] = f2b(v4[i][j]);
        *(u16x4*)(&ldsV[(cq + j) * LDSTR + rq * 4]) = vs;
      }
    }
    Kt += (size_t)64 * HE;
    Vt += (size_t)64 * HE;
    __syncthreads();

    // ---- S = Q K^T (16 q x 64 kv per wave), 8 MFMAs; pre-scaled log2 ----
    f32x4 sacc[4];
    #pragma unroll
    for (int n = 0; n < 4; ++n) {
      sacc[n][0] = 0.f; sacc[n][1] = 0.f; sacc[n][2] = 0.f; sacc[n][3] = 0.f;
    }
    #pragma unroll
    for (int n = 0; n < 4; ++n) {
      const int krow = n * 16 + ll;
      #pragma unroll
      for (int ek = 0; ek < 2; ++ek) {
        bf16x8 kf = *(const bf16x8*)(&ldsK[krow * LDSTR + ek * 32 + lg * 8]);
        sacc[n] = __builtin_amdgcn_mfma_f32_16x16x32_bf16(qf[ek], kf, sacc[n], 0, 0, 0);
      }
    }

    // ---- causal mask (diagonal tile only) ----
    if (t == qt) {
      const int s0 = t * 64;
      #pragma unroll
      for (int n = 0; n < 4; ++n) {
        const int kvg = s0 + n * 16 + ll;
        #pragma unroll
        for (int r = 0; r < 4; ++r) {
          if (kvg > q0 + lg * 4 + r) sacc[n][r] = -3.0e38f;
        }
      }
    }

    // ---- online softmax (per q-row: reg r within a 16-lane group) ----
    unsigned short* Pl = &ldsP[wave][0];
    #pragma unroll
    for (int r = 0; r < 4; ++r) {
      float mx = fmaxf(fmaxf(sacc[0][r], sacc[1][r]), fmaxf(sacc[2][r], sacc[3][r]));
      mx = fmaxf(mx, __shfl_xor(mx, 1));
      mx = fmaxf(mx, __shfl_xor(mx, 2));
      mx = fmaxf(mx, __shfl_xor(mx, 4));
      mx = fmaxf(mx, __shfl_xor(mx, 8));
      const float mnew = fmaxf(m_r[r], mx);
      const float corr = exp2f(m_r[r] - mnew);   // first tile: exp2(-inf)=0
      m_r[r] = mnew;
      float rs = 0.0f;
      #pragma unroll
      for (int n = 0; n < 4; ++n) {
        const float p = exp2f(sacc[n][r] - mnew);
        sacc[n][r] = p;
        rs += p;
      }
      rs += __shfl_xor(rs, 1);
      rs += __shfl_xor(rs, 2);
      rs += __shfl_xor(rs, 4);
      rs += __shfl_xor(rs, 8);
      l_r[r] = l_r[r] * corr + rs;
      #pragma unroll
      for (int n = 0; n < 4; ++n) oacc[n][r] *= corr;
      const int prow = lg * 4 + r;
      #pragma unroll
      for (int n = 0; n < 4; ++n)
        Pl[prow * LDSTR + n * 16 + ll] = f2b(sacc[n][r]);
    }

    // ---- O += P V (8 MFMAs) ----
    #pragma unroll
    for (int kk = 0; kk < 2; ++kk) {
      bf16x8 pf = *(const bf16x8*)(&Pl[ll * LDSTR + kk * 32 + lg * 8]);
      #pragma unroll
      for (int n = 0; n < 4; ++n) {
        bf16x8 vf = *(const bf16x8*)(&ldsV[(n * 16 + ll) * LDSTR + kk * 32 + lg * 8]);
        oacc[n] = __builtin_amdgcn_mfma_f32_16x16x32_bf16(pf, vf, oacc[n], 0, 0, 0);
      }
    }
  }

  // ---- epilogue: normalize and store f32 ----
  float* Ob = O + (((size_t)b * L_ + q0) * H_ + h) * E_;
  #pragma unroll
  for (int r = 0; r < 4; ++r) {
    const float inv = 1.0f / l_r[r];
    const int qrow = lg * 4 + r;
    #pragma unroll
    for (int n = 0; n < 4; ++n) {
      Ob[(size_t)qrow * HE + n * 16 + ll] = oacc[n][r] * inv;
    }
  }
}

extern "C" void kernel_launch(void* const* d_in, const int* in_sizes, int n_in,
                              void* d_out, int out_size, void* d_ws, size_t ws_size,
                              hipStream_t stream) {
  (void)in_sizes; (void)n_in; (void)out_size; (void)d_ws; (void)ws_size;
  const float* Q   = (const float*)d_in[0];
  const float* K   = (const float*)d_in[1];
  const float* V   = (const float*)d_in[2];
  // d_in[3] = attn_mask: ignored, causality applied analytically.
  const float* tau = (const float*)d_in[4];
  float* O = (float*)d_out;
  dim3 grid(L_ / 64, H_, B_), block(256);
  hipLaunchKernelGGL(attn_fwd, grid, block, 0, stream, Q, K, V, tau, O);
}

// Round 3
// 58.529 us; speedup vs baseline: 3.3058x; 1.9911x over previous
//
#include <hip/hip_runtime.h>
#include <hip/hip_bf16.h>
#include <math.h>

#define B_ 4
#define L_ 2048
#define H_ 8
#define E_ 64
#define HE 512   // H_*E_ : float stride between consecutive seq positions

typedef short bf16x8 __attribute__((ext_vector_type(8)));
typedef float f32x4 __attribute__((ext_vector_type(4)));
typedef float f32x2 __attribute__((ext_vector_type(2)));
typedef unsigned short u16x4 __attribute__((ext_vector_type(4)));
typedef unsigned short u16x8 __attribute__((ext_vector_type(8)));

__device__ __forceinline__ unsigned short f2b(float f) {
  return __builtin_bit_cast(unsigned short, (__hip_bfloat16)f);
}

// Flash attention fwd, causal, tau-scaled.
// Block = 8 waves = 128 q-rows (16/wave). KV tile 64. Swapped QK^T:
// sacc[m][r] = S[kv = 64t+16m+4lg+r][q = q0w+ll] -> softmax is lane-local
// (15 fmax + 2 shfl), and P feeds PV directly: the MFMA k-slots are
// kv-PERMUTED (pi = 32ek+16(j>>2)+4lg+(j&3)); V^T is read with the same
// permutation (2 x ds_read_b64 per frag), so no ldsP round-trip at all.
// K/V double-buffered in LDS (XOR-16B-granule swizzle, stride 64 elems),
// async-staged: global loads for t+1 issue before compute of t (T14).
__global__ __launch_bounds__(512, 4) void attn_fwd(
    const float* __restrict__ Q, const float* __restrict__ K,
    const float* __restrict__ V, const float* __restrict__ tau,
    float* __restrict__ O)
{
  // balanced remap: 512 blocks; CU c gets flat {c, c+256} -> qt {j, 15-j}
  // (per-CU tile count 34 = const); (b,h) fixed per flat%32 -> XCD locality.
  const int f  = blockIdx.x + 16 * (blockIdx.y + 8 * blockIdx.z);
  const int u  = f >> 5, hb = f & 31;
  const int h  = hb & 7, b = hb >> 3;
  const int qt = (u < 8) ? u : 23 - u;

  const int tid  = threadIdx.x;
  const int wave = tid >> 6, lane = tid & 63;
  const int lg = lane >> 4, ll = lane & 15;
  const int llm = ll & 7;

  __shared__ unsigned short ldsK[2][64 * 64];  // [kv][e], swizzled
  __shared__ unsigned short ldsV[2][64 * 64];  // transposed [d][kv], swizzled

  // fold 1/sqrt(E)*exp(tau)*log2(e) into Q -> softmax in exp2 domain
  const float qscale = 0.125f * expf(tau[b]) * 1.44269504088896f;
  const int q0w = qt * 128 + wave * 16;

  // Q fragment (B-operand of swapped QK^T): lane holds Q[q0w+ll][32ek+8lg+j]
  const float* Qb = Q + (((size_t)b * L_ + (q0w + ll)) * H_ + h) * E_;
  bf16x8 qf[2];
  #pragma unroll
  for (int ek = 0; ek < 2; ++ek) {
    f32x4 a = *(const f32x4*)(Qb + ek * 32 + lg * 8);
    f32x4 c = *(const f32x4*)(Qb + ek * 32 + lg * 8 + 4);
    #pragma unroll
    for (int j = 0; j < 4; ++j) {
      qf[ek][j]     = (short)f2b(a[j] * qscale);
      qf[ek][4 + j] = (short)f2b(c[j] * qscale);
    }
  }

  float m_run = -INFINITY, l_run = 0.0f;   // per-lane: stats of q = q0w+ll
  f32x4 oacc[4];
  #pragma unroll
  for (int n = 0; n < 4; ++n) {
    oacc[n][0] = 0.f; oacc[n][1] = 0.f; oacc[n][2] = 0.f; oacc[n][3] = 0.f;
  }

  // ---- staging mappings ----
  // K: thread -> row = tid>>3 (0..63), cols (tid&7)*8..+7  (2 f32x4 loads)
  // V: thread -> rows 4*(tid>>5)+i (i<4), cols (tid&31)*2..+1 (4 f32x2 loads)
  const int krow = tid >> 3, kcol = (tid & 7) * 8;
  const int vq = tid >> 5,  vc = (tid & 31) * 2;
  const float* Kp = K + ((size_t)b * L_ * H_ + h) * E_ + (size_t)krow * HE + kcol;
  const float* Vp = V + ((size_t)b * L_ * H_ + h) * E_ + (size_t)(4 * vq) * HE + vc;
  const int kw_off = krow * 64 + (((tid & 7) ^ (krow & 7)) << 3);

  const int nt = 2 * qt + 2;               // causal kv tiles for this block
  const int tmaxw = 2 * qt + (wave >> 2);  // this wave's diagonal tile

  // ---- prologue: stage tile 0 into buf 0 ----
  {
    f32x4 k0 = *(const f32x4*)(Kp);
    f32x4 k1 = *(const f32x4*)(Kp + 4);
    f32x2 v0 = *(const f32x2*)(Vp);
    f32x2 v1 = *(const f32x2*)(Vp + HE);
    f32x2 v2 = *(const f32x2*)(Vp + 2 * HE);
    f32x2 v3 = *(const f32x2*)(Vp + 3 * HE);
    u16x8 kw;
    #pragma unroll
    for (int j = 0; j < 4; ++j) { kw[j] = f2b(k0[j]); kw[4 + j] = f2b(k1[j]); }
    *(u16x8*)(&ldsK[0][kw_off]) = kw;
    #pragma unroll
    for (int jj = 0; jj < 2; ++jj) {
      const int row = vc + jj;
      u16x4 vw;
      vw[0] = f2b(v0[jj]); vw[1] = f2b(v1[jj]);
      vw[2] = f2b(v2[jj]); vw[3] = f2b(v3[jj]);
      *(u16x4*)(&ldsV[0][row * 64 + (((vq >> 1) ^ (row & 7)) << 3) + 4 * (vq & 1)]) = vw;
    }
  }
  __syncthreads();
  int cur = 0;

  for (int t = 0; t < nt; ++t) {
    const bool havenext = (t + 1 < nt);
    f32x4 k0, k1; f32x2 v0, v1, v2, v3;
    if (havenext) {          // T14: issue loads early, write to LDS late
      const float* Kn = Kp + (size_t)(t + 1) * 64 * HE;
      const float* Vn = Vp + (size_t)(t + 1) * 64 * HE;
      k0 = *(const f32x4*)(Kn);
      k1 = *(const f32x4*)(Kn + 4);
      v0 = *(const f32x2*)(Vn);
      v1 = *(const f32x2*)(Vn + HE);
      v2 = *(const f32x2*)(Vn + 2 * HE);
      v3 = *(const f32x2*)(Vn + 3 * HE);
    }

    if (t <= tmaxw) {        // waves fully ahead of diagonal skip compute
      const unsigned short* Kl = ldsK[cur];
      const unsigned short* Vl = ldsV[cur];

      // ---- S^T = K Q^T : 8 MFMAs ----
      f32x4 sacc[4];
      #pragma unroll
      for (int m = 0; m < 4; ++m) {
        sacc[m][0] = 0.f; sacc[m][1] = 0.f; sacc[m][2] = 0.f; sacc[m][3] = 0.f;
      }
      #pragma unroll
      for (int ek = 0; ek < 2; ++ek) {
        #pragma unroll
        for (int m = 0; m < 4; ++m) {
          bf16x8 kf = *(const bf16x8*)(Kl + (16 * m + ll) * 64 +
                                       ((((ek << 2) + lg) ^ llm) << 3));
          sacc[m] = __builtin_amdgcn_mfma_f32_16x16x32_bf16(kf, qf[ek], sacc[m], 0, 0, 0);
        }
      }

      // ---- causal mask (diagonal tile only) ----
      if (t == tmaxw) {
        const int dq = q0w + ll - 64 * t;   // keep kv_local <= dq
        #pragma unroll
        for (int m = 0; m < 4; ++m)
          #pragma unroll
          for (int r = 0; r < 4; ++r)
            if (16 * m + 4 * lg + r > dq) sacc[m][r] = -3.0e38f;
      }

      // ---- online softmax (lane-local row + 2 shfl across lg copies) ----
      float mx = sacc[0][0];
      #pragma unroll
      for (int m = 0; m < 4; ++m)
        #pragma unroll
        for (int r = 0; r < 4; ++r)
          mx = fmaxf(mx, sacc[m][r]);
      mx = fmaxf(mx, __shfl_xor(mx, 16));
      mx = fmaxf(mx, __shfl_xor(mx, 32));
      const float mnew = fmaxf(m_run, mx);
      const float corr = exp2f(m_run - mnew);   // tile 0: exp2(-inf)=0
      m_run = mnew;
      float rs = 0.0f;
      #pragma unroll
      for (int m = 0; m < 4; ++m)
        #pragma unroll
        for (int r = 0; r < 4; ++r) {
          const float p = exp2f(sacc[m][r] - mnew);
          sacc[m][r] = p;
          rs += p;
        }
      rs += __shfl_xor(rs, 16);
      rs += __shfl_xor(rs, 32);
      l_run = l_run * corr + rs;

      // rescale O (oacc rows are q = 4lg+r -> fetch corr from lane 4lg+r)
      #pragma unroll
      for (int r = 0; r < 4; ++r) {
        const float cr = __shfl(corr, 4 * lg + r);
        #pragma unroll
        for (int n = 0; n < 4; ++n) oacc[n][r] *= cr;
      }

      // ---- P frags: lane's own values, packed in permuted-kv order ----
      bf16x8 pf[2];
      #pragma unroll
      for (int ek = 0; ek < 2; ++ek)
        #pragma unroll
        for (int r = 0; r < 4; ++r) {
          pf[ek][r]     = (short)f2b(sacc[2 * ek][r]);
          pf[ek][4 + r] = (short)f2b(sacc[2 * ek + 1][r]);
        }

      // ---- O += P V : 8 MFMAs, V^T read with matching kv permutation ----
      #pragma unroll
      for (int ek = 0; ek < 2; ++ek) {
        #pragma unroll
        for (int n = 0; n < 4; ++n) {
          const int d = 16 * n + ll;
          const int base = d * 64 + 4 * (lg & 1);
          u16x4 lo = *(const u16x4*)(Vl + base +
                       ((((ek << 2) + (lg >> 1)) ^ llm) << 3));
          u16x4 hi = *(const u16x4*)(Vl + base +
                       ((((ek << 2) + 2 + (lg >> 1)) ^ llm) << 3));
          bf16x8 vf;
          #pragma unroll
          for (int i = 0; i < 4; ++i) {
            vf[i]     = (short)lo[i];
            vf[4 + i] = (short)hi[i];
          }
          oacc[n] = __builtin_amdgcn_mfma_f32_16x16x32_bf16(pf[ek], vf, oacc[n], 0, 0, 0);
        }
      }
    }

    if (havenext) {
      const int nb = cur ^ 1;
      u16x8 kw;
      #pragma unroll
      for (int j = 0; j < 4; ++j) { kw[j] = f2b(k0[j]); kw[4 + j] = f2b(k1[j]); }
      *(u16x8*)(&ldsK[nb][kw_off]) = kw;
      #pragma unroll
      for (int jj = 0; jj < 2; ++jj) {
        const int row = vc + jj;
        u16x4 vw;
        vw[0] = f2b(v0[jj]); vw[1] = f2b(v1[jj]);
        vw[2] = f2b(v2[jj]); vw[3] = f2b(v3[jj]);
        *(u16x4*)(&ldsV[nb][row * 64 + (((vq >> 1) ^ (row & 7)) << 3) + 4 * (vq & 1)]) = vw;
      }
      __syncthreads();
      cur = nb;
    }
  }

  // ---- epilogue: normalize and store f32 ----
  const float linv = 1.0f / l_run;           // valid for q = ll on lanes 0..15
  float* Ob = O + (((size_t)b * L_ + q0w) * H_ + h) * E_;
  #pragma unroll
  for (int r = 0; r < 4; ++r) {
    const float inv = __shfl(linv, 4 * lg + r);
    const int qrow = 4 * lg + r;
    #pragma unroll
    for (int n = 0; n < 4; ++n)
      Ob[(size_t)qrow * HE + 16 * n + ll] = oacc[n][r] * inv;
  }
}

extern "C" void kernel_launch(void* const* d_in, const int* in_sizes, int n_in,
                              void* d_out, int out_size, void* d_ws, size_t ws_size,
                              hipStream_t stream) {
  (void)in_sizes; (void)n_in; (void)out_size; (void)d_ws; (void)ws_size;
  const float* Q   = (const float*)d_in[0];
  const float* K   = (const float*)d_in[1];
  const float* V   = (const float*)d_in[2];
  // d_in[3] = attn_mask: ignored, causality applied analytically.
  const float* tau = (const float*)d_in[4];
  float* O = (float*)d_out;
  dim3 grid(L_ / 128, H_, B_), block(512);
  hipLaunchKernelGGL(attn_fwd, grid, block, 0, stream, Q, K, V, tau, O);
}